// Round 2
// baseline (56.284 us; speedup 1.0000x reference)
//
#include <hip/hip_runtime.h>

#define B_ 2
#define N_ 16384
#define M_ 8192
#define BLK 256
#define TN 16
#define CHUNK 128

typedef float f32x2 __attribute__((ext_vector_type(2)));
typedef float f32x4 __attribute__((ext_vector_type(4)));

// proven on HW (all-VGPR operands)
__device__ inline f32x2 pk_fma(f32x2 a, f32x2 b, f32x2 c) {
    f32x2 d;
    asm("v_pk_fma_f32 %0, %1, %2, %3" : "=v"(d) : "v"(a), "v"(b), "v"(c));
    return d;
}
__device__ inline float min3f(float a, float b, float c) {
    float d;
    asm("v_min3_f32 %0, %1, %2, %3" : "=v"(d) : "v"(a), "v"(b), "v"(c));
    return d;
}

// ---------------- reductions ----------------

__device__ inline float blk_reduce_max(float v, float* red) {
    #pragma unroll
    for (int off = 32; off; off >>= 1) v = fmaxf(v, __shfl_xor(v, off));
    int wid = threadIdx.x >> 6;
    int lane = threadIdx.x & 63;
    int nw = blockDim.x >> 6;
    if (lane == 0) red[wid] = v;
    __syncthreads();
    if (wid == 0) {
        v = (lane < nw) ? red[lane] : -3.402823466e38f;
        #pragma unroll
        for (int off = 32; off; off >>= 1) v = fmaxf(v, __shfl_xor(v, off));
        if (lane == 0) red[0] = v;
    }
    __syncthreads();
    v = red[0];
    __syncthreads();
    return v;
}

__device__ inline float blk_reduce_sum(float v, float* red) {
    #pragma unroll
    for (int off = 32; off; off >>= 1) v += __shfl_xor(v, off);
    int wid = threadIdx.x >> 6;
    int lane = threadIdx.x & 63;
    int nw = blockDim.x >> 6;
    if (lane == 0) red[wid] = v;
    __syncthreads();
    if (wid == 0) {
        v = (lane < nw) ? red[lane] : 0.0f;
        #pragma unroll
        for (int off = 32; off; off >>= 1) v += __shfl_xor(v, off);
        if (lane == 0) red[0] = v;
    }
    __syncthreads();
    v = red[0];
    __syncthreads();
    return v;
}

// ---------------- kernels ----------------

// grid = (B_*N_)/256 = 128 blocks. Also computes per-wave partial maxes of the
// weights (raceless: each wave writes its own slot), so finalize can skip the
// full-N max pass.
__global__ __launch_bounds__(256) void init_ws(const float* __restrict__ wts,
                                               unsigned int* min1, unsigned int* min2,
                                               float* __restrict__ wmax_part,
                                               float* out) {
    int i = blockIdx.x * 256 + threadIdx.x;
    if (i < B_ * N_) min1[i] = 0x7F7FFFFFu;  // FLT_MAX bits
    if (i < B_ * M_) min2[i] = 0x7F7FFFFFu;
    if (i == 0) out[0] = 0.0f;

    // i always < B_*N_ with this grid; wts is (B, N) flat.
    float v = wts[i];
    #pragma unroll
    for (int off = 32; off; off >>= 1) v = fmaxf(v, __shfl_xor(v, off));
    if ((threadIdx.x & 63) == 0)
        wmax_part[blockIdx.x * 4 + (threadIdx.x >> 6)] = v;  // 4 waves/block
}

// Fused both-direction pairwise-min sweep, packed-fp32 inner loop.
//   blocks [0,512):    owners = points1 rows (N), scan points2 (M)
//   blocks [512,1024): owners = points2 rows (M), scan points1 (N)
// TN=16 + CHUNK=128 keeps grid=1024 (4 blocks/CU = 4 waves/SIMD, round-1
// occupancy) while halving LDS-read frequency per pair-eval vs TN=8 (round-1
// was LDS-pipe co-saturated: per-CU LDS demand ~= per-CU VALU capacity).
// v_pk_fma_f32 is half-rate (4 cyc/wave), so VALU floor is ~24us; target is
// closing the 63% -> ~85% VALUBusy gap by relieving the LDS convoy.
// LDS stores CHUNK staged points as pairs {x0,x1,y0,y1 | z0,z1,w0,w1} with
// (x,y,z) pre-scaled by -2 and w = ||p||^2, read as 2x ds_read_b128 per pair.
__global__ __launch_bounds__(BLK) void min_pairwise_all(
        const float* __restrict__ p1, const float* __restrict__ p2,
        unsigned int* __restrict__ min1, unsigned int* __restrict__ min2) {
    __shared__ f32x4 sh4[CHUNK];   // (CHUNK/2 pairs) * 2 quads = 2 KiB

    int bid = blockIdx.x;
    const float* pa;
    const float* pb;
    unsigned int* mins;
    int NA, NB, bx, bin, b;
    if (bid < 512) {
        bx = bid & 3;               // 4 x-blocks * 4096 owners = 16384
        bin = (bid >> 2) & 63;      // 64 bins * 128 = 8192 scanned
        b = bid >> 8;
        pa = p1; pb = p2; mins = min1; NA = N_; NB = M_;
    } else {
        int t = bid - 512;
        bx = t & 1;                 // 2 x-blocks * 4096 owners = 8192
        bin = (t >> 1) & 127;       // 128 bins * 128 = 16384 scanned
        b = t >> 8;
        pa = p2; pb = p1; mins = min2; NA = M_; NB = N_;
    }

    // stage + pre-transform one chunk of the scanned set (pair-interleaved)
    if (threadIdx.x < CHUNK) {
        const float* pbb = pb + ((size_t)b * NB + bin * CHUNK) * 3;
        int i = threadIdx.x;
        float gx = pbb[3 * i], gy = pbb[3 * i + 1], gz = pbb[3 * i + 2];
        float* base = (float*)&sh4[(i >> 1) * 2] + (i & 1);
        base[0] = -2.0f * gx;
        base[2] = -2.0f * gy;
        base[4] = -2.0f * gz;
        base[6] = fmaf(gx, gx, fmaf(gy, gy, gz * gz));
    }
    __syncthreads();

    // owners: load once, duplicate into both packed halves (one-time cost)
    const float* pab = pa + (size_t)b * NA * 3;
    const int nbase = bx * (BLK * TN) + threadIdx.x;

    f32x2 X[TN], Y[TN], Z[TN];
    float mn[TN];
    #pragma unroll
    for (int j = 0; j < TN; j++) {
        int n = nbase + j * BLK;
        float x = pab[3 * n], y = pab[3 * n + 1], z = pab[3 * n + 2];
        X[j] = (f32x2){x, x};
        Y[j] = (f32x2){y, y};
        Z[j] = (f32x2){z, z};
        mn[j] = 3.402823466e38f;
    }

    #pragma unroll 2
    for (int p = 0; p < CHUNK / 2; p++) {
        f32x4 lo = sh4[2 * p];
        f32x4 hi = sh4[2 * p + 1];
        f32x2 Qx = __builtin_shufflevector(lo, lo, 0, 1);
        f32x2 Qy = __builtin_shufflevector(lo, lo, 2, 3);
        f32x2 Qz = __builtin_shufflevector(hi, hi, 0, 1);
        f32x2 Qw = __builtin_shufflevector(hi, hi, 2, 3);
        #pragma unroll
        for (int j = 0; j < TN; j++) {
            f32x2 v = pk_fma(Z[j], Qz, Qw);
            v = pk_fma(Y[j], Qy, v);
            v = pk_fma(X[j], Qx, v);
            mn[j] = min3f(mn[j], v.x, v.y);
        }
    }

    #pragma unroll
    for (int j = 0; j < TN; j++) {
        int n = nbase + j * BLK;
        float sqa = fmaf(X[j].x, X[j].x, fmaf(Y[j].x, Y[j].x, Z[j].x * Z[j].x));
        // squared distances are non-negative: float bits order as uint
        atomicMin(&mins[(size_t)b * NA + n], __float_as_uint(mn[j] + sqa));
    }
}

__global__ __launch_bounds__(1024) void finalize_kernel(
        const float* __restrict__ wts,
        const float* __restrict__ min1,
        const float* __restrict__ min2,
        const float* __restrict__ wmax_part,
        float* __restrict__ out) {
    __shared__ float red[16];
    int b = blockIdx.x;
    const float* wb = wts + b * N_;
    const float* m1 = min1 + b * N_;
    const float* m2 = min2 + b * M_;

    // max from precomputed per-wave partials (256 per batch)
    float lmax = (threadIdx.x < 256) ? wmax_part[b * 256 + threadIdx.x]
                                     : -3.402823466e38f;
    float gmax = blk_reduce_max(lmax, red);

    float se = 0.0f, swm = 0.0f;
    for (int i = threadIdx.x; i < N_ / 4; i += blockDim.x) {
        f32x4 w4 = ((const f32x4*)wb)[i];
        f32x4 m4 = ((const f32x4*)m1)[i];
        #pragma unroll
        for (int k = 0; k < 4; k++) {
            float e = expf(w4[k] - gmax);
            se += e;
            swm += e * m4[k];
        }
    }
    float tse = blk_reduce_sum(se, red);
    float tswm = blk_reduce_sum(swm, red);

    float sm2 = 0.0f;
    for (int i = threadIdx.x; i < M_ / 4; i += blockDim.x) {
        f32x4 m4 = ((const f32x4*)m2)[i];
        sm2 += (m4.x + m4.y) + (m4.z + m4.w);
    }
    float tsm2 = blk_reduce_sum(sm2, red);

    if (threadIdx.x == 0)
        atomicAdd(out, (tswm / tse + tsm2 * (1.0f / (float)M_)) * (1.0f / (float)B_));
}

// ---------------- launch ----------------

extern "C" void kernel_launch(void* const* d_in, const int* in_sizes, int n_in,
                              void* d_out, int out_size, void* d_ws, size_t ws_size,
                              hipStream_t stream) {
    const float* p1  = (const float*)d_in[0];  // (B, N, 3)
    const float* p2  = (const float*)d_in[1];  // (B, M, 3)
    const float* wts = (const float*)d_in[2];  // (B, N)
    float* out = (float*)d_out;

    unsigned int* min1 = (unsigned int*)d_ws;        // B*N
    unsigned int* min2 = min1 + B_ * N_;             // B*M
    float* wmax_part = (float*)(min2 + B_ * M_);     // 128 blocks * 4 waves = 512

    init_ws<<<dim3((B_ * N_) / 256), dim3(256), 0, stream>>>(wts, min1, min2,
                                                             wmax_part, out);
    min_pairwise_all<<<dim3(1024), dim3(BLK), 0, stream>>>(p1, p2, min1, min2);
    finalize_kernel<<<dim3(B_), dim3(1024), 0, stream>>>(
        wts, (const float*)min1, (const float*)min2, wmax_part, out);
}

// Round 3
// 56.170 us; speedup vs baseline: 1.0020x; 1.0020x over previous
//
#include <hip/hip_runtime.h>

#define B_ 2
#define N_ 16384
#define M_ 8192
#define BLK 256
#define TN 16
#define CHUNK 128

typedef float f32x4 __attribute__((ext_vector_type(4)));

__device__ inline float min3f(float a, float b, float c) {
    float d;
    asm("v_min3_f32 %0, %1, %2, %3" : "=v"(d) : "v"(a), "v"(b), "v"(c));
    return d;
}

// ---------------- reductions ----------------

__device__ inline float blk_reduce_max(float v, float* red) {
    #pragma unroll
    for (int off = 32; off; off >>= 1) v = fmaxf(v, __shfl_xor(v, off));
    int wid = threadIdx.x >> 6;
    int lane = threadIdx.x & 63;
    int nw = blockDim.x >> 6;
    if (lane == 0) red[wid] = v;
    __syncthreads();
    if (wid == 0) {
        v = (lane < nw) ? red[lane] : -3.402823466e38f;
        #pragma unroll
        for (int off = 32; off; off >>= 1) v = fmaxf(v, __shfl_xor(v, off));
        if (lane == 0) red[0] = v;
    }
    __syncthreads();
    v = red[0];
    __syncthreads();
    return v;
}

__device__ inline float blk_reduce_sum(float v, float* red) {
    #pragma unroll
    for (int off = 32; off; off >>= 1) v += __shfl_xor(v, off);
    int wid = threadIdx.x >> 6;
    int lane = threadIdx.x & 63;
    int nw = blockDim.x >> 6;
    if (lane == 0) red[wid] = v;
    __syncthreads();
    if (wid == 0) {
        v = (lane < nw) ? red[lane] : 0.0f;
        #pragma unroll
        for (int off = 32; off; off >>= 1) v += __shfl_xor(v, off);
        if (lane == 0) red[0] = v;
    }
    __syncthreads();
    v = red[0];
    __syncthreads();
    return v;
}

// ---------------- kernels ----------------

// grid = (B_*N_)/256 = 128 blocks. Also computes per-wave partial maxes of the
// weights (raceless: each wave writes its own slot), so finalize can skip the
// full-N max pass.
__global__ __launch_bounds__(256) void init_ws(const float* __restrict__ wts,
                                               unsigned int* min1, unsigned int* min2,
                                               float* __restrict__ wmax_part,
                                               float* out) {
    int i = blockIdx.x * 256 + threadIdx.x;
    if (i < B_ * N_) min1[i] = 0x7F7FFFFFu;  // FLT_MAX bits
    if (i < B_ * M_) min2[i] = 0x7F7FFFFFu;
    if (i == 0) out[0] = 0.0f;

    // i always < B_*N_ with this grid; wts is (B, N) flat.
    float v = wts[i];
    #pragma unroll
    for (int off = 32; off; off >>= 1) v = fmaxf(v, __shfl_xor(v, off));
    if ((threadIdx.x & 63) == 0)
        wmax_part[blockIdx.x * 4 + (threadIdx.x >> 6)] = v;  // 4 waves/block
}

// Fused both-direction pairwise-min sweep, SCALAR v_fma_f32 inner loop.
// Round-2 finding: v_pk_fma_f32 is quarter-rate on gfx950 (demand model at
// 8 cyc/wave64 gives 109M SIMD-cycles ~= 112M available at 45.7us -> the pipe
// was saturated; occupancy/LDS changes were null because the instruction
// stream was the limiter). Scalar v_fma_f32 is full-rate (2 cyc): per 2
// scanned points per owner = 6 fma + 1 min3 = 14 cyc per 128 pair-evals
// -> 58.7M cycle demand -> ~24us floor at 100% pipe.
//   blocks [0,512):    owners = points1 rows (N), scan points2 (M)
//   blocks [512,1024): owners = points2 rows (M), scan points1 (N)
// LDS stores CHUNK staged points as pairs {x0,x1,y0,y1 | z0,z1,w0,w1} with
// (x,y,z) pre-scaled by -2 and w = ||p||^2, read as 2x ds_read_b128 per pair.
__global__ __launch_bounds__(BLK) void min_pairwise_all(
        const float* __restrict__ p1, const float* __restrict__ p2,
        unsigned int* __restrict__ min1, unsigned int* __restrict__ min2) {
    __shared__ f32x4 sh4[CHUNK];   // (CHUNK/2 pairs) * 2 quads = 2 KiB

    int bid = blockIdx.x;
    const float* pa;
    const float* pb;
    unsigned int* mins;
    int NA, NB, bx, bin, b;
    if (bid < 512) {
        bx = bid & 3;               // 4 x-blocks * 4096 owners = 16384
        bin = (bid >> 2) & 63;      // 64 bins * 128 = 8192 scanned
        b = bid >> 8;
        pa = p1; pb = p2; mins = min1; NA = N_; NB = M_;
    } else {
        int t = bid - 512;
        bx = t & 1;                 // 2 x-blocks * 4096 owners = 8192
        bin = (t >> 1) & 127;       // 128 bins * 128 = 16384 scanned
        b = t >> 8;
        pa = p2; pb = p1; mins = min2; NA = M_; NB = N_;
    }

    // stage + pre-transform one chunk of the scanned set (pair-interleaved)
    if (threadIdx.x < CHUNK) {
        const float* pbb = pb + ((size_t)b * NB + bin * CHUNK) * 3;
        int i = threadIdx.x;
        float gx = pbb[3 * i], gy = pbb[3 * i + 1], gz = pbb[3 * i + 2];
        float* base = (float*)&sh4[(i >> 1) * 2] + (i & 1);
        base[0] = -2.0f * gx;
        base[2] = -2.0f * gy;
        base[4] = -2.0f * gz;
        base[6] = fmaf(gx, gx, fmaf(gy, gy, gz * gz));
    }
    __syncthreads();

    // owners: one scalar copy each (no packing)
    const float* pab = pa + (size_t)b * NA * 3;
    const int nbase = bx * (BLK * TN) + threadIdx.x;

    float X[TN], Y[TN], Z[TN], mn[TN];
    #pragma unroll
    for (int j = 0; j < TN; j++) {
        int n = nbase + j * BLK;
        X[j] = pab[3 * n];
        Y[j] = pab[3 * n + 1];
        Z[j] = pab[3 * n + 2];
        mn[j] = 3.402823466e38f;
    }

    #pragma unroll 2
    for (int p = 0; p < CHUNK / 2; p++) {
        f32x4 lo = sh4[2 * p];       // {-2x0, -2x1, -2y0, -2y1}
        f32x4 hi = sh4[2 * p + 1];   // {-2z0, -2z1,   w0,   w1}
        #pragma unroll
        for (int j = 0; j < TN; j++) {
            float a = fmaf(Z[j], hi.x, hi.z);
            a = fmaf(Y[j], lo.z, a);
            a = fmaf(X[j], lo.x, a);
            float c = fmaf(Z[j], hi.y, hi.w);
            c = fmaf(Y[j], lo.w, c);
            c = fmaf(X[j], lo.y, c);
            mn[j] = min3f(mn[j], a, c);
        }
    }

    #pragma unroll
    for (int j = 0; j < TN; j++) {
        int n = nbase + j * BLK;
        float sqa = fmaf(X[j], X[j], fmaf(Y[j], Y[j], Z[j] * Z[j]));
        // squared distances are non-negative: float bits order as uint
        atomicMin(&mins[(size_t)b * NA + n], __float_as_uint(mn[j] + sqa));
    }
}

__global__ __launch_bounds__(1024) void finalize_kernel(
        const float* __restrict__ wts,
        const float* __restrict__ min1,
        const float* __restrict__ min2,
        const float* __restrict__ wmax_part,
        float* __restrict__ out) {
    __shared__ float red[16];
    int b = blockIdx.x;
    const float* wb = wts + b * N_;
    const float* m1 = min1 + b * N_;
    const float* m2 = min2 + b * M_;

    // max from precomputed per-wave partials (256 per batch)
    float lmax = (threadIdx.x < 256) ? wmax_part[b * 256 + threadIdx.x]
                                     : -3.402823466e38f;
    float gmax = blk_reduce_max(lmax, red);

    float se = 0.0f, swm = 0.0f;
    for (int i = threadIdx.x; i < N_ / 4; i += blockDim.x) {
        f32x4 w4 = ((const f32x4*)wb)[i];
        f32x4 m4 = ((const f32x4*)m1)[i];
        #pragma unroll
        for (int k = 0; k < 4; k++) {
            float e = expf(w4[k] - gmax);
            se += e;
            swm += e * m4[k];
        }
    }
    float tse = blk_reduce_sum(se, red);
    float tswm = blk_reduce_sum(swm, red);

    float sm2 = 0.0f;
    for (int i = threadIdx.x; i < M_ / 4; i += blockDim.x) {
        f32x4 m4 = ((const f32x4*)m2)[i];
        sm2 += (m4.x + m4.y) + (m4.z + m4.w);
    }
    float tsm2 = blk_reduce_sum(sm2, red);

    if (threadIdx.x == 0)
        atomicAdd(out, (tswm / tse + tsm2 * (1.0f / (float)M_)) * (1.0f / (float)B_));
}

// ---------------- launch ----------------

extern "C" void kernel_launch(void* const* d_in, const int* in_sizes, int n_in,
                              void* d_out, int out_size, void* d_ws, size_t ws_size,
                              hipStream_t stream) {
    const float* p1  = (const float*)d_in[0];  // (B, N, 3)
    const float* p2  = (const float*)d_in[1];  // (B, M, 3)
    const float* wts = (const float*)d_in[2];  // (B, N)
    float* out = (float*)d_out;

    unsigned int* min1 = (unsigned int*)d_ws;        // B*N
    unsigned int* min2 = min1 + B_ * N_;             // B*M
    float* wmax_part = (float*)(min2 + B_ * M_);     // 128 blocks * 4 waves = 512

    init_ws<<<dim3((B_ * N_) / 256), dim3(256), 0, stream>>>(wts, min1, min2,
                                                             wmax_part, out);
    min_pairwise_all<<<dim3(1024), dim3(BLK), 0, stream>>>(p1, p2, min1, min2);
    finalize_kernel<<<dim3(B_), dim3(1024), 0, stream>>>(
        wts, (const float*)min1, (const float*)min2, wmax_part, out);
}

// Round 4
// 55.660 us; speedup vs baseline: 1.0112x; 1.0092x over previous
//
#include <hip/hip_runtime.h>

#define B_ 2
#define N_ 16384
#define M_ 8192

typedef float f32x4 __attribute__((ext_vector_type(4)));
typedef short s16x8 __attribute__((ext_vector_type(8)));

__device__ inline float min3f(float a, float b, float c) {
    float d;
    asm("v_min3_f32 %0, %1, %2, %3" : "=v"(d) : "v"(a), "v"(b), "v"(c));
    return d;
}

// RNE f32 -> bf16 (bits)
__device__ inline unsigned short f2bf(float f) {
    unsigned int u = __float_as_uint(f);
    u += 0x7FFFu + ((u >> 16) & 1u);
    return (unsigned short)(u >> 16);
}
__device__ inline float bf2f(unsigned short h) {
    return __uint_as_float(((unsigned int)h) << 16);
}
// 3-way bf16 split: v ~= h + m + l to ~2^-24 rel
__device__ inline void split3(float v, unsigned short& hb, unsigned short& mb,
                              unsigned short& lb) {
    hb = f2bf(v);
    float r1 = v - bf2f(hb);
    mb = f2bf(r1);
    float r2 = r1 - bf2f(mb);
    lb = f2bf(r2);
}

// ---------------- reductions ----------------

__device__ inline float blk_reduce_max(float v, float* red) {
    #pragma unroll
    for (int off = 32; off; off >>= 1) v = fmaxf(v, __shfl_xor(v, off));
    int wid = threadIdx.x >> 6;
    int lane = threadIdx.x & 63;
    int nw = blockDim.x >> 6;
    if (lane == 0) red[wid] = v;
    __syncthreads();
    if (wid == 0) {
        v = (lane < nw) ? red[lane] : -3.402823466e38f;
        #pragma unroll
        for (int off = 32; off; off >>= 1) v = fmaxf(v, __shfl_xor(v, off));
        if (lane == 0) red[0] = v;
    }
    __syncthreads();
    v = red[0];
    __syncthreads();
    return v;
}

__device__ inline float blk_reduce_sum(float v, float* red) {
    #pragma unroll
    for (int off = 32; off; off >>= 1) v += __shfl_xor(v, off);
    int wid = threadIdx.x >> 6;
    int lane = threadIdx.x & 63;
    int nw = blockDim.x >> 6;
    if (lane == 0) red[wid] = v;
    __syncthreads();
    if (wid == 0) {
        v = (lane < nw) ? red[lane] : 0.0f;
        #pragma unroll
        for (int off = 32; off; off >>= 1) v += __shfl_xor(v, off);
        if (lane == 0) red[0] = v;
    }
    __syncthreads();
    v = red[0];
    __syncthreads();
    return v;
}

// ---------------- kernels ----------------

__global__ __launch_bounds__(256) void init_ws(const float* __restrict__ wts,
                                               unsigned int* min1, unsigned int* min2,
                                               float* __restrict__ wmax_part,
                                               float* out) {
    int i = blockIdx.x * 256 + threadIdx.x;
    if (i < B_ * N_) min1[i] = 0x7F7FFFFFu;  // FLT_MAX bits
    if (i < B_ * M_) min2[i] = 0x7F7FFFFFu;
    if (i == 0) out[0] = 0.0f;

    float v = wts[i];
    #pragma unroll
    for (int off = 32; off; off >>= 1) v = fmaxf(v, __shfl_xor(v, off));
    if ((threadIdx.x & 63) == 0)
        wmax_part[blockIdx.x * 4 + (threadIdx.x >> 6)] = v;  // 4 waves/block
}

// Single-pass MFMA chamfer sweep. Each 16x16x32 bf16 MFMA emits a full 16x16
// tile of EXACT-ish squared distances:
//   K slots 0-17: 6 product groups of the 3-way bf16 splits of u=-2*x and y
//                 (hh,hm,mh,hl,lh,mm per dim; dropped ml/lm/ll ~2^-24 rel)
//   K slots 18-20: sq1[n] split x 1 ;  21-23: 1 x sq2[m] split ; 24-31: 0
// Both A and B use the same lane->(row/col, k-slot) map, so the slot pairing is
// correct for ANY hardware k ordering (layout-robust).
// Each distance is computed ONCE (268M vs 537M in the two-pass VALU kernel,
// which sits at its 58.7M-SIMD-cycle fp32 floor = the measured 44us).
// min1 (over m, per row): 4 in-reg vmin per tile. min2 (over n, per col): col
// is lane-fixed -> 2 min3 per tile + 2 shfl cross-group + LDS combine.
// Block: 256 owner rows x 256 scanned cols; grid 64*32*2 = 4096.
__global__ __launch_bounds__(256) void chamfer_mfma(
        const float* __restrict__ p1, const float* __restrict__ p2,
        unsigned int* __restrict__ min1, unsigned int* __restrict__ min2) {
    __shared__ s16x8 Ash[16][64];        // 16 owner tiles  x 64 lanes x 16B = 16KB
    __shared__ s16x8 Bsh[16][64];        // 16 scan  tiles  x 64 lanes x 16B = 16KB
    __shared__ float m2sh[4][16][16];    // wave x tile x col = 4KB

    const int bid = blockIdx.x;
    const int b   = bid >> 11;           // 2048 blocks per batch
    const int rr  = bid & 2047;
    const int ob  = rr >> 5;             // 64 owner blocks
    const int bin = rr & 31;             // 32 scan bins
    const int nb  = ob * 256;
    const int mb  = bin * 256;

    const int t = threadIdx.x;
    const short ONE = (short)0x3F80;     // bf16(1.0)

    // ---- stage A: owner rows (u = -2x, sq1 = x.x) ----
    {
        const float* px = p1 + ((size_t)b * N_ + nb + t) * 3;
        float x0 = px[0], x1 = px[1], x2 = px[2];
        float sq = fmaf(x0, x0, fmaf(x1, x1, x2 * x2));
        unsigned short uh[3], um[3], ul[3], s1[3];
        split3(-2.f * x0, uh[0], um[0], ul[0]);
        split3(-2.f * x1, uh[1], um[1], ul[1]);
        split3(-2.f * x2, uh[2], um[2], ul[2]);
        split3(sq, s1[0], s1[1], s1[2]);
        s16x8 g0 = {(short)uh[0], (short)uh[1], (short)uh[2], (short)uh[0],
                    (short)uh[1], (short)uh[2], (short)um[0], (short)um[1]};
        s16x8 g1 = {(short)um[2], (short)uh[0], (short)uh[1], (short)uh[2],
                    (short)ul[0], (short)ul[1], (short)ul[2], (short)um[0]};
        s16x8 g2 = {(short)um[1], (short)um[2], (short)s1[0], (short)s1[1],
                    (short)s1[2], ONE, ONE, ONE};
        s16x8 g3 = {0, 0, 0, 0, 0, 0, 0, 0};
        int tl = t >> 4, c = t & 15;
        Ash[tl][ 0 + c] = g0;
        Ash[tl][16 + c] = g1;
        Ash[tl][32 + c] = g2;
        Ash[tl][48 + c] = g3;
    }
    // ---- stage B: scanned cols (y, sq2 = y.y) ----
    {
        const float* py = p2 + ((size_t)b * M_ + mb + t) * 3;
        float y0 = py[0], y1 = py[1], y2 = py[2];
        float sq = fmaf(y0, y0, fmaf(y1, y1, y2 * y2));
        unsigned short yh[3], ym[3], yl[3], s2[3];
        split3(y0, yh[0], ym[0], yl[0]);
        split3(y1, yh[1], ym[1], yl[1]);
        split3(y2, yh[2], ym[2], yl[2]);
        split3(sq, s2[0], s2[1], s2[2]);
        s16x8 g0 = {(short)yh[0], (short)yh[1], (short)yh[2], (short)ym[0],
                    (short)ym[1], (short)ym[2], (short)yh[0], (short)yh[1]};
        s16x8 g1 = {(short)yh[2], (short)yl[0], (short)yl[1], (short)yl[2],
                    (short)yh[0], (short)yh[1], (short)yh[2], (short)ym[0]};
        s16x8 g2 = {(short)ym[1], (short)ym[2], ONE, ONE, ONE,
                    (short)s2[0], (short)s2[1], (short)s2[2]};
        s16x8 g3 = {0, 0, 0, 0, 0, 0, 0, 0};
        int tl = t >> 4, c = t & 15;
        Bsh[tl][ 0 + c] = g0;
        Bsh[tl][16 + c] = g1;
        Bsh[tl][32 + c] = g2;
        Bsh[tl][48 + c] = g3;
    }
    __syncthreads();

    const int w = t >> 6, l = t & 63;

    s16x8 Af[4];
    #pragma unroll
    for (int r = 0; r < 4; r++) Af[r] = Ash[4 * w + r][l];

    f32x4 mn1v[4];
    #pragma unroll
    for (int r = 0; r < 4; r++)
        mn1v[r] = (f32x4){3.402823466e38f, 3.402823466e38f,
                          3.402823466e38f, 3.402823466e38f};

    const f32x4 zacc = {0.f, 0.f, 0.f, 0.f};

    #pragma unroll 4
    for (int mt = 0; mt < 16; mt++) {
        s16x8 Bf = Bsh[mt][l];
        float m2v = 3.402823466e38f;
        #pragma unroll
        for (int r = 0; r < 4; r++) {
            f32x4 acc = __builtin_amdgcn_mfma_f32_16x16x32_bf16(Af[r], Bf, zacc, 0, 0, 0);
            mn1v[r].x = fminf(mn1v[r].x, acc.x);
            mn1v[r].y = fminf(mn1v[r].y, acc.y);
            mn1v[r].z = fminf(mn1v[r].z, acc.z);
            mn1v[r].w = fminf(mn1v[r].w, acc.w);
            m2v = min3f(m2v, acc.x, acc.y);
            m2v = min3f(m2v, acc.z, acc.w);
        }
        // col-min across the 4 row-groups (lanes ^16, ^32)
        m2v = fminf(m2v, __shfl_xor(m2v, 16));
        m2v = fminf(m2v, __shfl_xor(m2v, 32));
        if (l < 16) m2sh[w][mt][l] = m2v;
    }

    // ---- epilogue: min1 (reduce over the 16 cols held across lanes l&15) ----
    unsigned int* m1g = min1 + (size_t)b * N_;
    #pragma unroll
    for (int r = 0; r < 4; r++) {
        #pragma unroll
        for (int q = 0; q < 4; q++) {
            float v = mn1v[r][q];
            v = fminf(v, __shfl_xor(v, 1));
            v = fminf(v, __shfl_xor(v, 2));
            v = fminf(v, __shfl_xor(v, 4));
            v = fminf(v, __shfl_xor(v, 8));
            if ((l & 15) == 0) {
                int row = nb + (4 * w + r) * 16 + (l >> 4) * 4 + q;
                // distances non-negative: float bits order as uint
                atomicMin(&m1g[row], __float_as_uint(v));
            }
        }
    }

    __syncthreads();
    // ---- epilogue: min2 (combine 4 wave partials per col, one atomic/col) ----
    {
        float v = fminf(fminf(m2sh[0][t >> 4][t & 15], m2sh[1][t >> 4][t & 15]),
                        fminf(m2sh[2][t >> 4][t & 15], m2sh[3][t >> 4][t & 15]));
        atomicMin(&min2[(size_t)b * M_ + mb + t], __float_as_uint(v));
    }
}

__global__ __launch_bounds__(1024) void finalize_kernel(
        const float* __restrict__ wts,
        const float* __restrict__ min1,
        const float* __restrict__ min2,
        const float* __restrict__ wmax_part,
        float* __restrict__ out) {
    __shared__ float red[16];
    int b = blockIdx.x;
    const float* wb = wts + b * N_;
    const float* m1 = min1 + b * N_;
    const float* m2 = min2 + b * M_;

    float lmax = (threadIdx.x < 256) ? wmax_part[b * 256 + threadIdx.x]
                                     : -3.402823466e38f;
    float gmax = blk_reduce_max(lmax, red);

    float se = 0.0f, swm = 0.0f;
    for (int i = threadIdx.x; i < N_ / 4; i += blockDim.x) {
        f32x4 w4 = ((const f32x4*)wb)[i];
        f32x4 m4 = ((const f32x4*)m1)[i];
        #pragma unroll
        for (int k = 0; k < 4; k++) {
            float e = expf(w4[k] - gmax);
            se += e;
            swm += e * m4[k];
        }
    }
    float tse = blk_reduce_sum(se, red);
    float tswm = blk_reduce_sum(swm, red);

    float sm2 = 0.0f;
    for (int i = threadIdx.x; i < M_ / 4; i += blockDim.x) {
        f32x4 m4 = ((const f32x4*)m2)[i];
        sm2 += (m4.x + m4.y) + (m4.z + m4.w);
    }
    float tsm2 = blk_reduce_sum(sm2, red);

    if (threadIdx.x == 0)
        atomicAdd(out, (tswm / tse + tsm2 * (1.0f / (float)M_)) * (1.0f / (float)B_));
}

// ---------------- launch ----------------

extern "C" void kernel_launch(void* const* d_in, const int* in_sizes, int n_in,
                              void* d_out, int out_size, void* d_ws, size_t ws_size,
                              hipStream_t stream) {
    const float* p1  = (const float*)d_in[0];  // (B, N, 3)
    const float* p2  = (const float*)d_in[1];  // (B, M, 3)
    const float* wts = (const float*)d_in[2];  // (B, N)
    float* out = (float*)d_out;

    unsigned int* min1 = (unsigned int*)d_ws;        // B*N
    unsigned int* min2 = min1 + B_ * N_;             // B*M
    float* wmax_part = (float*)(min2 + B_ * M_);     // 128 blocks * 4 waves = 512

    init_ws<<<dim3((B_ * N_) / 256), dim3(256), 0, stream>>>(wts, min1, min2,
                                                             wmax_part, out);
    chamfer_mfma<<<dim3(4096), dim3(256), 0, stream>>>(p1, p2, min1, min2);
    finalize_kernel<<<dim3(B_), dim3(1024), 0, stream>>>(
        wts, (const float*)min1, (const float*)min2, wmax_part, out);
}